// Round 1
// 641.192 us; speedup vs baseline: 1.1916x; 1.1916x over previous
//
#include <hip/hip_runtime.h>
#include <math.h>

#define Bc 8
#define Lc 4096
#define Hc 8
#define Dc 64
#define CHUNK 512
#define NCH (Lc / CHUNK)   // 8 key-chunks for flash-attn partials
#define VCH 16
#define VROWS (Lc / VCH)   // 256 rows per cumsum chunk

// DPP rotate-add within the 16-lane row: full-rate VALU, no LDS pipe.
template<int CTRL>
__device__ __forceinline__ float dpp_radd(float v) {
    int y = __builtin_amdgcn_update_dpp(0, __float_as_int(v), CTRL, 0xF, 0xF, true);
    return v + __int_as_float(y);
}
// sum across the 16 lanes of a DPP row via ror 8,4,2,1 (all lanes get total)
__device__ __forceinline__ float row16_sum(float p) {
    p = dpp_radd<0x128>(p);   // row_ror:8
    p = dpp_radd<0x124>(p);   // row_ror:4
    p = dpp_radd<0x122>(p);   // row_ror:2
    p = dpp_radd<0x121>(p);   // row_ror:1
    return p;
}

// ---------------------------------------------------------------- kernel 1
// M[b,h,q] = max_s(Q[q]·K[idx[q,s]]) - (sum_s Q[q]·K[idx[q,s]])/L
// Wave = one q. 4 groups of 16 lanes; group g handles sample s = it*4+g.
// Fully unrolled (S compile-time): all idx loads + all K gathers issue up
// front; 16-lane dot reduced with 4 DPP adds (no ds_swizzle chains, no LDS).
template<int S>
__global__ __launch_bounds__(256) void k_meas_t(
    const float* __restrict__ Q, const float* __restrict__ K,
    const int* __restrict__ idx, float* __restrict__ M)
{
    constexpr int NIT = (S + 3) / 4;
    int b = blockIdx.z, h = blockIdx.y;
    int w = threadIdx.x >> 6, lane = threadIdx.x & 63;
    int q = blockIdx.x * 4 + w;
    int grp = lane >> 4, gl = lane & 15;

    const float4 qv = *(const float4*)(Q + (((size_t)b * Lc + q) * Hc + h) * Dc + gl * 4);
    const int* ip = idx + (size_t)q * S + grp;          // sample s = it*4+grp
    const float* Kb = K + ((size_t)b * Lc * Hc + h) * Dc + gl * 4;

    // preload all row indices (16-lane-uniform addresses -> L1 broadcast)
    int rows[NIT];
    #pragma unroll
    for (int it = 0; it < NIT - 1; it++) rows[it] = ip[it * 4];   // s<=4*NIT-5 < S
    {   // tail: s = 4*(NIT-1)+grp may exceed S-1 -> clamp (in-bounds), mask later
        int s = 4 * (NIT - 1) + grp;
        rows[NIT - 1] = ip[(s < S) ? 4 * (NIT - 1) : (S - 1 - grp)];
    }

    float mloc = -INFINITY, sloc = 0.f;
    #pragma unroll
    for (int it = 0; it < NIT; it++) {
        const float4 kw = *(const float4*)(Kb + ((size_t)rows[it] << 9)); // Hc*Dc=512
        float p = kw.x * qv.x + kw.y * qv.y + kw.z * qv.z + kw.w * qv.w;
        p = row16_sum(p);                 // all 16 lanes hold the full dot
        int s = it * 4 + grp;
        if (s < S) { mloc = fmaxf(mloc, p); sloc += p; }   // compile-time true except tail
    }
    // combine across the 4 groups (each group's lanes identical)
    mloc = fmaxf(mloc, __shfl_xor(mloc, 16, 64));
    mloc = fmaxf(mloc, __shfl_xor(mloc, 32, 64));
    sloc += __shfl_xor(sloc, 16, 64);
    sloc += __shfl_xor(sloc, 32, 64);

    if (lane == 0)
        M[((size_t)(b * Hc + h)) * Lc + q] = mloc - sloc * (1.0f / (float)Lc);
}

// runtime-S fallback (same math, non-unrolled) — not used for the fixed shape
__global__ __launch_bounds__(256) void k_meas_dyn(
    const float* __restrict__ Q, const float* __restrict__ K,
    const int* __restrict__ idx, float* __restrict__ M, int S)
{
    int b = blockIdx.z, h = blockIdx.y;
    int w = threadIdx.x >> 6, lane = threadIdx.x & 63;
    int q = blockIdx.x * 4 + w;
    int grp = lane >> 4, gl = lane & 15;

    const float4 qv = *(const float4*)(Q + (((size_t)b * Lc + q) * Hc + h) * Dc + gl * 4);
    const int* ip = idx + (size_t)q * S;
    const float* Kb = K + ((size_t)b * Lc * Hc + h) * Dc + gl * 4;

    float mloc = -INFINITY, sloc = 0.f;
    int niter = (S + 3) >> 2;
    for (int it = 0; it < niter; it++) {
        int s = it * 4 + grp;
        int ii = s < S ? s : S - 1;
        int row = ip[ii];
        const float4 kw = *(const float4*)(Kb + ((size_t)row << 9));
        float p = kw.x * qv.x + kw.y * qv.y + kw.z * qv.z + kw.w * qv.w;
        p = row16_sum(p);
        if (s < S) { mloc = fmaxf(mloc, p); sloc += p; }
    }
    mloc = fmaxf(mloc, __shfl_xor(mloc, 16, 64));
    mloc = fmaxf(mloc, __shfl_xor(mloc, 32, 64));
    sloc += __shfl_xor(sloc, 16, 64);
    sloc += __shfl_xor(sloc, 32, 64);
    if (lane == 0)
        M[((size_t)(b * Hc + h)) * Lc + q] = mloc - sloc * (1.0f / (float)Lc);
}

// ---------------------------------------------------------------- kernel 2
// top-U per (b,h): values live in REGISTERS as (monotonic-fp32<<32)|idx keys.
// Per round: cached per-thread best -> wave shuffle-max -> 4-entry LDS max ->
// one barrier (double-buffered); only the winner rescans its 16 registers.
__global__ __launch_bounds__(256) void k_topk(
    const float* __restrict__ M, int* __restrict__ top, int U)
{
    int bh = blockIdx.x;
    int tid = threadIdx.x;
    const float* m = M + (size_t)bh * Lc;

    unsigned long long key[16];
    #pragma unroll
    for (int j = 0; j < 16; j++) {
        int i = tid * 16 + j;
        unsigned int u = __float_as_uint(m[i]);
        u ^= (unsigned int)(((int)u >> 31)) | 0x80000000u;   // order-preserving map
        key[j] = ((unsigned long long)u << 32) | (unsigned int)i;
    }
    unsigned long long myb = key[0];
    #pragma unroll
    for (int j = 1; j < 16; j++) myb = key[j] > myb ? key[j] : myb;

    __shared__ unsigned long long swave[2][4];

    for (int u = 0; u < U; u++) {
        unsigned long long wmax = myb;
        #pragma unroll
        for (int o = 32; o >= 1; o >>= 1) {
            unsigned long long t = __shfl_xor(wmax, o, 64);
            wmax = t > wmax ? t : wmax;
        }
        if ((tid & 63) == 0) swave[u & 1][tid >> 6] = wmax;
        __syncthreads();
        unsigned long long w0 = swave[u & 1][0], w1 = swave[u & 1][1];
        unsigned long long w2 = swave[u & 1][2], w3 = swave[u & 1][3];
        unsigned long long a = w0 > w1 ? w0 : w1;
        unsigned long long c = w2 > w3 ? w2 : w3;
        unsigned long long win = a > c ? a : c;
        int widx = (int)(win & 0xFFFFFFFFu);
        if (tid == 0) top[(size_t)bh * U + u] = widx;
        if (tid == (widx >> 4)) {
            #pragma unroll
            for (int j = 0; j < 16; j++) if (j == (widx & 15)) key[j] = 0ull;
            unsigned long long b2 = key[0];
            #pragma unroll
            for (int j = 1; j < 16; j++) b2 = key[j] > b2 ? key[j] : b2;
            myb = b2;
        }
        // next iter writes the other swave buffer; its barrier orders reuse
    }
}

// ---------------------------------------------------------------- kernel 3a
// per-chunk column sums of V (for the scan's base offsets)
__global__ __launch_bounds__(256) void k_vsum(
    const float* __restrict__ V, float* __restrict__ bsum)
{
    int b = blockIdx.z, h = blockIdx.y, c = blockIdx.x;
    int d = threadIdx.x & 63, g = threadIdx.x >> 6;
    __shared__ float part[4][64];
    float s = 0.f;
    int r0 = c * VROWS;
    for (int r = r0 + g; r < r0 + VROWS; r += 4)
        s += V[(((size_t)b * Lc + r) * Hc + h) * Dc + d];
    part[g][d] = s;
    __syncthreads();
    if (g == 0)
        bsum[(((size_t)(b * Hc + h)) * VCH + c) * 64 + d] =
            part[0][d] + part[1][d] + part[2][d] + part[3][d];
}

// ---------------------------------------------------------------- kernel 3b
// scan within each 256-row chunk, offset by prefix of chunk sums
__global__ __launch_bounds__(256) void k_scan(
    const float* __restrict__ V, const float* __restrict__ bsum,
    float* __restrict__ out)
{
    int b = blockIdx.z, h = blockIdx.y, c = blockIdx.x;
    int d = threadIdx.x & 63, g = threadIdx.x >> 6;
    int bh = b * Hc + h;
    __shared__ float gtot[4][64];
    __shared__ float goff[4][64];

    float base = 0.f;
    for (int cc = 0; cc < c; cc++)
        base += bsum[((size_t)bh * VCH + cc) * 64 + d];

    int gs = c * VROWS + g * 64;
    float gsum = 0.f;
    for (int r = gs; r < gs + 64; r++)
        gsum += V[(((size_t)b * Lc + r) * Hc + h) * Dc + d];
    gtot[g][d] = gsum;
    __syncthreads();
    if (g == 0) {
        float run = base;
        for (int gg = 0; gg < 4; gg++) { goff[gg][d] = run; run += gtot[gg][d]; }
    }
    __syncthreads();
    float run = goff[g][d];
    for (int r = gs; r < gs + 64; r++) {
        size_t o = (((size_t)b * Lc + r) * Hc + h) * Dc + d;
        run += V[o];
        out[o] = run;
    }
}

// ---------------------------------------------------------------- kernel 4
// chunked flash attention over the selected queries per (b,h).
__global__ __launch_bounds__(256) void k_attn2(
    const float* __restrict__ Q, const float* __restrict__ K,
    const float* __restrict__ V, const int* __restrict__ top,
    float* __restrict__ Opart, float* __restrict__ Mp, float* __restrict__ Lp,
    int U)
{
    int b = blockIdx.z, h = blockIdx.y, c = blockIdx.x;
    int bh = b * Hc + h;
    int tid = threadIdx.x;
    int lane = tid & 63, g = tid >> 6;

    __shared__ float sQ[45][64];     // scaled queries
    __shared__ int   sqi[45];
    __shared__ float sKT[64][65];    // K tile, transposed, padded
    __shared__ float sVT[64][65];    // V tile, transposed, padded
    __shared__ float sP[45][64];     // probs handoff (lane=k -> lane=d)

    if (tid < U) sqi[tid] = top[(size_t)bh * U + tid];
    __syncthreads();
    for (int u = g; u < U; u += 4)
        sQ[u][lane] = Q[(((size_t)b * Lc + sqi[u]) * Hc + h) * Dc + lane] * 0.125f;

    // wave-local query list (wave g owns u = g, g+4, ...)
    int nj = 0, uj[12], qj[12];
    for (int u = g; u < U; u += 4) { uj[nj] = u; qj[nj] = sqi[u]; nj++; }

    float m_r[12], l_r[12], o_r[12];
    #pragma unroll
    for (int j = 0; j < 12; j++) { m_r[j] = -INFINITY; l_r[j] = 0.f; o_r[j] = 0.f; }

    int k0c = c * CHUNK;
    for (int t = 0; t < CHUNK / 64; t++) {
        int k0 = k0c + t * 64;
        __syncthreads();   // previous tile fully consumed
        {   // stage K,V transposed: thread (row=lane, d-group=g)
            const float* kp = K + (((size_t)b * Lc + k0 + lane) * Hc + h) * Dc + g * 16;
            const float* vp = V + (((size_t)b * Lc + k0 + lane) * Hc + h) * Dc + g * 16;
            #pragma unroll
            for (int i = 0; i < 4; i++) {
                float4 kw = *(const float4*)(kp + i * 4);
                float4 vw = *(const float4*)(vp + i * 4);
                int d0 = g * 16 + i * 4;
                sKT[d0+0][lane] = kw.x; sKT[d0+1][lane] = kw.y;
                sKT[d0+2][lane] = kw.z; sKT[d0+3][lane] = kw.w;
                sVT[d0+0][lane] = vw.x; sVT[d0+1][lane] = vw.y;
                sVT[d0+2][lane] = vw.z; sVT[d0+3][lane] = vw.w;
            }
        }
        __syncthreads();

        for (int j = 0; j < nj; j++) {
            int q = qj[j];
            if (k0 > q) continue;      // wave-uniform: tile fully masked
            int u = uj[j];
            // ---- QK^T: lane = key
            float s = 0.f;
            #pragma unroll
            for (int d = 0; d < 64; d += 4) {
                float k0v = sKT[d+0][lane];
                float k1v = sKT[d+1][lane];
                float k2v = sKT[d+2][lane];
                float k3v = sKT[d+3][lane];
                float4 qv = *(const float4*)&sQ[u][d];   // broadcast
                s += qv.x*k0v + qv.y*k1v + qv.z*k2v + qv.w*k3v;
            }
            if (k0 + lane > q) s = -INFINITY;
            // ---- online softmax update
            float tm = s;
            #pragma unroll
            for (int o = 32; o >= 1; o >>= 1) tm = fmaxf(tm, __shfl_xor(tm, o, 64));
            float mnew = fmaxf(m_r[j], tm);              // finite: lane 0 unmasked
            float p = __expf(s - mnew);
            float ps = p;
            #pragma unroll
            for (int o = 32; o >= 1; o >>= 1) ps += __shfl_xor(ps, o, 64);
            float alpha = __expf(m_r[j] - mnew);         // exp(-inf)=0 on first hit
            l_r[j] = l_r[j] * alpha + ps;
            m_r[j] = mnew;
            sP[u][lane] = p;
            // ---- PV: lane = d  (same wave wrote sP row; lgkmcnt orders it)
            float pv = 0.f;
            #pragma unroll
            for (int k = 0; k < 64; k += 4) {
                float v0 = sVT[lane][k+0];
                float v1 = sVT[lane][k+1];
                float v2 = sVT[lane][k+2];
                float v3 = sVT[lane][k+3];
                float4 pw = *(const float4*)&sP[u][k];   // broadcast
                pv += pw.x*v0 + pw.y*v1 + pw.z*v2 + pw.w*v3;
            }
            o_r[j] = o_r[j] * alpha + pv;
        }
    }

    for (int j = 0; j < nj; j++) {
        int u = uj[j];
        size_t s0 = ((size_t)bh * NCH + c) * U + u;
        Opart[s0 * 64 + lane] = o_r[j];
        if (lane == 0) { Mp[s0] = m_r[j]; Lp[s0] = l_r[j]; }
    }
}

// ---------------------------------------------------------------- kernel 5
// merge chunk partials and scatter into the cumsum output rows.
__global__ __launch_bounds__(64) void k_combine(
    const float* __restrict__ Opart, const float* __restrict__ Mp,
    const float* __restrict__ Lp, const int* __restrict__ top,
    float* __restrict__ out, int U)
{
    int b = blockIdx.z, h = blockIdx.y, u = blockIdx.x;
    int bh = b * Hc + h;
    int lane = threadIdx.x;
    int q = top[(size_t)bh * U + u];

    float mv[NCH], lv[NCH];
    float mg = -INFINITY;
    #pragma unroll
    for (int c = 0; c < NCH; c++) {
        size_t s0 = ((size_t)bh * NCH + c) * U + u;
        mv[c] = Mp[s0]; lv[c] = Lp[s0];
        mg = fmaxf(mg, mv[c]);
    }
    float Ls = 0.f, o = 0.f;
    #pragma unroll
    for (int c = 0; c < NCH; c++) {
        if (lv[c] > 0.f) {
            float w = __expf(mv[c] - mg);
            Ls += w * lv[c];
            o  += w * Opart[(((size_t)bh * NCH + c) * U + u) * 64 + lane];
        }
    }
    out[(((size_t)b * Lc + q) * Hc + h) * Dc + lane] = o / Ls;
}

extern "C" void kernel_launch(void* const* d_in, const int* in_sizes, int n_in,
                              void* d_out, int out_size, void* d_ws, size_t ws_size,
                              hipStream_t stream)
{
    const float* Q = (const float*)d_in[0];
    const float* K = (const float*)d_in[1];
    const float* V = (const float*)d_in[2];
    const int* idx = (const int*)d_in[3];
    float* out = (float*)d_out;

    int S = in_sizes[3] / Lc;   // sample_k == u == 45

    // ws layout (bytes). M occupies [0, 8MB) during meas/topk, then is dead;
    // attn partials reuse that region (stream order guarantees safety).
    char* ws = (char*)d_ws;
    float* M     = (float*)ws;                          // 1 MB
    float* Opart = (float*)ws;                          // 5.90 MB (overlaps M)
    float* Mp    = (float*)(ws + 6291456);              // 90 KB
    float* Lp    = (float*)(ws + 6422528);              // 90 KB
    float* bsum  = (float*)(ws + 6815744);              // 256 KB
    int*   top   = (int*)  (ws + 8388608);              // 11.5 KB

    dim3 blk(256);
    if (S == 45)
        k_meas_t<45><<<dim3(Lc / 4, Hc, Bc), blk, 0, stream>>>(Q, K, idx, M);
    else
        k_meas_dyn  <<<dim3(Lc / 4, Hc, Bc), blk, 0, stream>>>(Q, K, idx, M, S);
    k_topk   <<<dim3(Bc * Hc),        blk, 0, stream>>>(M, top, S);
    k_vsum   <<<dim3(VCH, Hc, Bc),    blk, 0, stream>>>(V, bsum);
    k_scan   <<<dim3(VCH, Hc, Bc),    blk, 0, stream>>>(V, bsum, out);
    k_attn2  <<<dim3(NCH, Hc, Bc),    blk, 0, stream>>>(Q, K, V, top, Opart, Mp, Lp, S);
    k_combine<<<dim3(S, Hc, Bc), dim3(64), 0, stream>>>(Opart, Mp, Lp, top, out, S);
}

// Round 2
// 636.204 us; speedup vs baseline: 1.2009x; 1.0078x over previous
//
#include <hip/hip_runtime.h>
#include <math.h>

#define Bc 8
#define Lc 4096
#define Hc 8
#define Dc 64
#define NCH 8              // equal-WORK chunks (sqrt-spaced causal boundaries)
#define VCH 16
#define VROWS (Lc / VCH)   // 256 rows per cumsum chunk

// equal-work causal chunk boundaries: b_c ~= L*(1-sqrt(1-c/8)), 64-aligned
__constant__ int c_cb[NCH + 1] = {0, 256, 576, 832, 1216, 1600, 2048, 2624, 4096};

// ---------------------------------------------------------------- DPP helpers
template<int CTRL>
__device__ __forceinline__ float dpp_mov(float v) {
    return __int_as_float(__builtin_amdgcn_update_dpp(
        0, __float_as_int(v), CTRL, 0xF, 0xF, true));
}
template<int CTRL>
__device__ __forceinline__ float dpp_radd(float v) {
    return v + dpp_mov<CTRL>(v);
}
// sum across the 16 lanes of a DPP row via ror 8,4,2,1 (all lanes get total)
__device__ __forceinline__ float row16_sum(float p) {
    p = dpp_radd<0x128>(p); p = dpp_radd<0x124>(p);
    p = dpp_radd<0x122>(p); p = dpp_radd<0x121>(p);
    return p;
}
// full-wave max: 4 DPP (VALU pipe) + 2 swizzles
__device__ __forceinline__ float wmax64(float v) {
    v = fmaxf(v, dpp_mov<0x128>(v));
    v = fmaxf(v, dpp_mov<0x124>(v));
    v = fmaxf(v, dpp_mov<0x122>(v));
    v = fmaxf(v, dpp_mov<0x121>(v));
    v = fmaxf(v, __shfl_xor(v, 16, 64));
    return fmaxf(v, __shfl_xor(v, 32, 64));
}
__device__ __forceinline__ float wsum64(float v) {
    v = row16_sum(v);
    v += __shfl_xor(v, 16, 64);
    return v + __shfl_xor(v, 32, 64);
}

// ---------------------------------------------------------------- kernel 1
// M[b,h,q] = max_s(Q[q]·K[idx[q,s]]) - (sum_s Q[q]·K[idx[q,s]])/L
template<int S>
__global__ __launch_bounds__(256) void k_meas_t(
    const float* __restrict__ Q, const float* __restrict__ K,
    const int* __restrict__ idx, float* __restrict__ M)
{
    constexpr int NIT = (S + 3) / 4;
    int b = blockIdx.z, h = blockIdx.y;
    int w = threadIdx.x >> 6, lane = threadIdx.x & 63;
    int q = blockIdx.x * 4 + w;
    int grp = lane >> 4, gl = lane & 15;

    const float4 qv = *(const float4*)(Q + (((size_t)b * Lc + q) * Hc + h) * Dc + gl * 4);
    const int* ip = idx + (size_t)q * S + grp;
    const float* Kb = K + ((size_t)b * Lc * Hc + h) * Dc + gl * 4;

    int rows[NIT];
    #pragma unroll
    for (int it = 0; it < NIT - 1; it++) rows[it] = ip[it * 4];
    {
        int s = 4 * (NIT - 1) + grp;
        rows[NIT - 1] = ip[(s < S) ? 4 * (NIT - 1) : (S - 1 - grp)];
    }

    float mloc = -INFINITY, sloc = 0.f;
    #pragma unroll
    for (int it = 0; it < NIT; it++) {
        const float4 kw = *(const float4*)(Kb + ((size_t)rows[it] << 9));
        float p = kw.x * qv.x + kw.y * qv.y + kw.z * qv.z + kw.w * qv.w;
        p = row16_sum(p);
        int s = it * 4 + grp;
        if (s < S) { mloc = fmaxf(mloc, p); sloc += p; }
    }
    mloc = fmaxf(mloc, __shfl_xor(mloc, 16, 64));
    mloc = fmaxf(mloc, __shfl_xor(mloc, 32, 64));
    sloc += __shfl_xor(sloc, 16, 64);
    sloc += __shfl_xor(sloc, 32, 64);

    if (lane == 0)
        M[((size_t)(b * Hc + h)) * Lc + q] = mloc - sloc * (1.0f / (float)Lc);
}

__global__ __launch_bounds__(256) void k_meas_dyn(
    const float* __restrict__ Q, const float* __restrict__ K,
    const int* __restrict__ idx, float* __restrict__ M, int S)
{
    int b = blockIdx.z, h = blockIdx.y;
    int w = threadIdx.x >> 6, lane = threadIdx.x & 63;
    int q = blockIdx.x * 4 + w;
    int grp = lane >> 4, gl = lane & 15;

    const float4 qv = *(const float4*)(Q + (((size_t)b * Lc + q) * Hc + h) * Dc + gl * 4);
    const int* ip = idx + (size_t)q * S;
    const float* Kb = K + ((size_t)b * Lc * Hc + h) * Dc + gl * 4;

    float mloc = -INFINITY, sloc = 0.f;
    int niter = (S + 3) >> 2;
    for (int it = 0; it < niter; it++) {
        int s = it * 4 + grp;
        int ii = s < S ? s : S - 1;
        int row = ip[ii];
        const float4 kw = *(const float4*)(Kb + ((size_t)row << 9));
        float p = kw.x * qv.x + kw.y * qv.y + kw.z * qv.z + kw.w * qv.w;
        p = row16_sum(p);
        if (s < S) { mloc = fmaxf(mloc, p); sloc += p; }
    }
    mloc = fmaxf(mloc, __shfl_xor(mloc, 16, 64));
    mloc = fmaxf(mloc, __shfl_xor(mloc, 32, 64));
    sloc += __shfl_xor(sloc, 16, 64);
    sloc += __shfl_xor(sloc, 32, 64);
    if (lane == 0)
        M[((size_t)(b * Hc + h)) * Lc + q] = mloc - sloc * (1.0f / (float)Lc);
}

// ---------------------------------------------------------------- kernel 2
__global__ __launch_bounds__(256) void k_topk(
    const float* __restrict__ M, int* __restrict__ top, int U)
{
    int bh = blockIdx.x;
    int tid = threadIdx.x;
    const float* m = M + (size_t)bh * Lc;

    unsigned long long key[16];
    #pragma unroll
    for (int j = 0; j < 16; j++) {
        int i = tid * 16 + j;
        unsigned int u = __float_as_uint(m[i]);
        u ^= (unsigned int)(((int)u >> 31)) | 0x80000000u;
        key[j] = ((unsigned long long)u << 32) | (unsigned int)i;
    }
    unsigned long long myb = key[0];
    #pragma unroll
    for (int j = 1; j < 16; j++) myb = key[j] > myb ? key[j] : myb;

    __shared__ unsigned long long swave[2][4];

    for (int u = 0; u < U; u++) {
        unsigned long long wmax = myb;
        #pragma unroll
        for (int o = 32; o >= 1; o >>= 1) {
            unsigned long long t = __shfl_xor(wmax, o, 64);
            wmax = t > wmax ? t : wmax;
        }
        if ((tid & 63) == 0) swave[u & 1][tid >> 6] = wmax;
        __syncthreads();
        unsigned long long w0 = swave[u & 1][0], w1 = swave[u & 1][1];
        unsigned long long w2 = swave[u & 1][2], w3 = swave[u & 1][3];
        unsigned long long a = w0 > w1 ? w0 : w1;
        unsigned long long c = w2 > w3 ? w2 : w3;
        unsigned long long win = a > c ? a : c;
        int widx = (int)(win & 0xFFFFFFFFu);
        if (tid == 0) top[(size_t)bh * U + u] = widx;
        if (tid == (widx >> 4)) {
            #pragma unroll
            for (int j = 0; j < 16; j++) if (j == (widx & 15)) key[j] = 0ull;
            unsigned long long b2 = key[0];
            #pragma unroll
            for (int j = 1; j < 16; j++) b2 = key[j] > b2 ? key[j] : b2;
            myb = b2;
        }
    }
}

// ---------------------------------------------------------------- kernel 3a
__global__ __launch_bounds__(256) void k_vsum(
    const float* __restrict__ V, float* __restrict__ bsum)
{
    int b = blockIdx.z, h = blockIdx.y, c = blockIdx.x;
    int d = threadIdx.x & 63, g = threadIdx.x >> 6;
    __shared__ float part[4][64];
    float s = 0.f;
    int r0 = c * VROWS;
    for (int r = r0 + g; r < r0 + VROWS; r += 4)
        s += V[(((size_t)b * Lc + r) * Hc + h) * Dc + d];
    part[g][d] = s;
    __syncthreads();
    if (g == 0)
        bsum[(((size_t)(b * Hc + h)) * VCH + c) * 64 + d] =
            part[0][d] + part[1][d] + part[2][d] + part[3][d];
}

// ---------------------------------------------------------------- kernel 3b
__global__ __launch_bounds__(256) void k_scan(
    const float* __restrict__ V, const float* __restrict__ bsum,
    float* __restrict__ out)
{
    int b = blockIdx.z, h = blockIdx.y, c = blockIdx.x;
    int d = threadIdx.x & 63, g = threadIdx.x >> 6;
    int bh = b * Hc + h;
    __shared__ float gtot[4][64];
    __shared__ float goff[4][64];

    float base = 0.f;
    for (int cc = 0; cc < c; cc++)
        base += bsum[((size_t)bh * VCH + cc) * 64 + d];

    int gs = c * VROWS + g * 64;
    float gsum = 0.f;
    for (int r = gs; r < gs + 64; r++)
        gsum += V[(((size_t)b * Lc + r) * Hc + h) * Dc + d];
    gtot[g][d] = gsum;
    __syncthreads();
    if (g == 0) {
        float run = base;
        for (int gg = 0; gg < 4; gg++) { goff[gg][d] = run; run += gtot[gg][d]; }
    }
    __syncthreads();
    float run = goff[g][d];
    for (int r = gs; r < gs + 64; r++) {
        size_t o = (((size_t)b * Lc + r) * Hc + h) * Dc + d;
        run += V[o];
        out[o] = run;
    }
}

// ---------------------------------------------------------------- kernel 4
// flash attention over selected queries; equal-work causal chunks,
// XOR-swizzled K tile (b128 reads), 4-query register blocking, DPP softmax.
__global__ __launch_bounds__(256) void k_attn2(
    const float* __restrict__ Q, const float* __restrict__ K,
    const float* __restrict__ V, const int* __restrict__ top,
    float* __restrict__ Opart, float* __restrict__ Mp, float* __restrict__ Lp,
    int U)
{
    int b = blockIdx.z, h = blockIdx.y, c = blockIdx.x;
    int bh = b * Hc + h;
    int tid = threadIdx.x;
    int lane = tid & 63, g = tid >> 6;

    __shared__ float4 sK4[64][16];   // K tile: row k, physical blk = lb ^ (k&7)
    __shared__ float  sVT[64][65];   // V tile transposed [d][k], stride-65 pad
    __shared__ float  sQ[45][64];    // scaled queries
    __shared__ float  sP[45][64];    // probs handoff (lane=k -> lane=d)
    __shared__ int    sqi[45];

    if (tid < U) sqi[tid] = top[(size_t)bh * U + tid];
    __syncthreads();
    for (int u = g; u < U; u += 4)
        sQ[u][lane] = Q[(((size_t)b * Lc + sqi[u]) * Hc + h) * Dc + lane] * 0.125f;

    // block-uniform max query (tile cutoff)
    int qbm = 0;
    for (int u = 0; u < U; u++) qbm = max(qbm, sqi[u]);

    // wave-local padded query list, compile-time indices only (no scratch)
    int qq[16], tt[16];
    int ulast = g + (((U - 1 - g) >> 2) << 2);     // last valid u for this wave
    #pragma unroll
    for (int i = 0; i < 12; i++) {
        int u = g + 4 * i;
        u = (u <= ulast) ? u : ulast;
        tt[i] = u; qq[i] = sqi[u];
    }
    #pragma unroll
    for (int i = 12; i < 16; i++) { tt[i] = tt[11]; qq[i] = 0x7FFFFFFF; }
    // bitonic sort ascending by qq (16-wide network, fully unrolled)
    #pragma unroll
    for (int kk = 2; kk <= 16; kk <<= 1) {
        #pragma unroll
        for (int jj = kk >> 1; jj > 0; jj >>= 1) {
            #pragma unroll
            for (int ii = 0; ii < 16; ii++) {
                int ll = ii ^ jj;
                if (ll > ii) {
                    bool up = ((ii & kk) == 0);
                    bool sw = up ? (qq[ii] > qq[ll]) : (qq[ii] < qq[ll]);
                    if (sw) {
                        int tq = qq[ii]; qq[ii] = qq[ll]; qq[ll] = tq;
                        int tu = tt[ii]; tt[ii] = tt[ll]; tt[ll] = tu;
                    }
                }
            }
        }
    }

    float m_r[12], l_r[12], o_r[12];
    #pragma unroll
    for (int j = 0; j < 12; j++) { m_r[j] = -INFINITY; l_r[j] = 0.f; o_r[j] = 0.f; }

    int k0c = c_cb[c], k1c = c_cb[c + 1];
    int ntile = 0;
    if (qbm >= k0c) {
        int lastk = min(qbm, k1c - 1);
        ntile = (lastk - k0c) / 64 + 1;
    }
    int kswz = lane & 7;

    for (int t = 0; t < ntile; t++) {
        int k0 = k0c + t * 64;
        __syncthreads();   // previous tile fully consumed
        {   // stage: thread (row=lane, d-group=g); K swizzled b128, V transposed
            const float* kp = K + (((size_t)b * Lc + k0 + lane) * Hc + h) * Dc + g * 16;
            const float* vp = V + (((size_t)b * Lc + k0 + lane) * Hc + h) * Dc + g * 16;
            #pragma unroll
            for (int i = 0; i < 4; i++) {
                float4 kw = *(const float4*)(kp + i * 4);
                float4 vw = *(const float4*)(vp + i * 4);
                int lb = g * 4 + i;
                sK4[lane][lb ^ (lane & 7)] = kw;
                int d0 = lb * 4;
                sVT[d0+0][lane] = vw.x; sVT[d0+1][lane] = vw.y;
                sVT[d0+2][lane] = vw.z; sVT[d0+3][lane] = vw.w;
            }
        }
        __syncthreads();

        #pragma unroll
        for (int j0 = 0; j0 < 12; j0 += 4) {
            if (k0 > qq[j0 + 3]) continue;   // sorted ascending: group max
            int ua = tt[j0], ub = tt[j0+1], uc = tt[j0+2], ud = tt[j0+3];
            // ---- QK^T: lane = key; 16 swizzled b128 K reads shared by 4 queries
            float s0 = 0.f, s1 = 0.f, s2 = 0.f, s3 = 0.f;
            #pragma unroll
            for (int lb = 0; lb < 16; lb++) {
                float4 kb = sK4[lane][lb ^ kswz];
                float4 qa = *(const float4*)&sQ[ua][lb * 4];
                float4 qb = *(const float4*)&sQ[ub][lb * 4];
                float4 qc = *(const float4*)&sQ[uc][lb * 4];
                float4 qd = *(const float4*)&sQ[ud][lb * 4];
                s0 += kb.x*qa.x + kb.y*qa.y + kb.z*qa.z + kb.w*qa.w;
                s1 += kb.x*qb.x + kb.y*qb.y + kb.z*qb.z + kb.w*qb.w;
                s2 += kb.x*qc.x + kb.y*qc.y + kb.z*qc.z + kb.w*qc.w;
                s3 += kb.x*qd.x + kb.y*qd.y + kb.z*qd.z + kb.w*qd.w;
            }
            // ---- online softmax (4 independent chains -> ILP)
            float a0, a1, a2, a3;
#define SLOT(jj, sv, av) { \
            float sA = (k0 + lane > qq[jj]) ? -INFINITY : sv; \
            float tm = wmax64(sA); \
            float mnew = fmaxf(m_r[jj], tm); \
            float p = __expf(sA - mnew); \
            float ps = wsum64(p); \
            av = __expf(m_r[jj] - mnew); \
            m_r[jj] = mnew; \
            l_r[jj] = l_r[jj] * av + ps; \
            sP[tt[jj]][lane] = p; }
            SLOT(j0+0, s0, a0)
            SLOT(j0+1, s1, a1)
            SLOT(j0+2, s2, a2)
            SLOT(j0+3, s3, a3)
#undef SLOT
            // ---- PV: lane = d; V reads shared by 4 queries
            float p0 = 0.f, p1 = 0.f, p2 = 0.f, p3 = 0.f;
            #pragma unroll
            for (int k = 0; k < 64; k += 4) {
                float v0 = sVT[lane][k+0], v1 = sVT[lane][k+1];
                float v2 = sVT[lane][k+2], v3 = sVT[lane][k+3];
                float4 wa = *(const float4*)&sP[ua][k];
                float4 wb = *(const float4*)&sP[ub][k];
                float4 wc = *(const float4*)&sP[uc][k];
                float4 wd = *(const float4*)&sP[ud][k];
                p0 += wa.x*v0 + wa.y*v1 + wa.z*v2 + wa.w*v3;
                p1 += wb.x*v0 + wb.y*v1 + wb.z*v2 + wb.w*v3;
                p2 += wc.x*v0 + wc.y*v1 + wc.z*v2 + wc.w*v3;
                p3 += wd.x*v0 + wd.y*v1 + wd.z*v2 + wd.w*v3;
            }
            o_r[j0+0] = o_r[j0+0] * a0 + p0;
            o_r[j0+1] = o_r[j0+1] * a1 + p1;
            o_r[j0+2] = o_r[j0+2] * a2 + p2;
            o_r[j0+3] = o_r[j0+3] * a3 + p3;
        }
    }

    // duplicates write identical values to identical addresses (safe)
    #pragma unroll
    for (int j = 0; j < 12; j++) {
        int u = tt[j];
        size_t s0 = ((size_t)bh * NCH + c) * U + u;
        Opart[s0 * 64 + lane] = o_r[j];
        if (lane == 0) { Mp[s0] = m_r[j]; Lp[s0] = l_r[j]; }
    }
}

// ---------------------------------------------------------------- kernel 5
__global__ __launch_bounds__(64) void k_combine(
    const float* __restrict__ Opart, const float* __restrict__ Mp,
    const float* __restrict__ Lp, const int* __restrict__ top,
    float* __restrict__ out, int U)
{
    int b = blockIdx.z, h = blockIdx.y, u = blockIdx.x;
    int bh = b * Hc + h;
    int lane = threadIdx.x;
    int q = top[(size_t)bh * U + u];

    float mv[NCH], lv[NCH];
    float mg = -INFINITY;
    #pragma unroll
    for (int c = 0; c < NCH; c++) {
        size_t s0 = ((size_t)bh * NCH + c) * U + u;
        mv[c] = Mp[s0]; lv[c] = Lp[s0];
        mg = fmaxf(mg, mv[c]);
    }
    float Ls = 0.f, o = 0.f;
    #pragma unroll
    for (int c = 0; c < NCH; c++) {
        if (lv[c] > 0.f) {
            float w = __expf(mv[c] - mg);
            Ls += w * lv[c];
            o  += w * Opart[(((size_t)bh * NCH + c) * U + u) * 64 + lane];
        }
    }
    out[(((size_t)b * Lc + q) * Hc + h) * Dc + lane] = o / Ls;
}

extern "C" void kernel_launch(void* const* d_in, const int* in_sizes, int n_in,
                              void* d_out, int out_size, void* d_ws, size_t ws_size,
                              hipStream_t stream)
{
    const float* Q = (const float*)d_in[0];
    const float* K = (const float*)d_in[1];
    const float* V = (const float*)d_in[2];
    const int* idx = (const int*)d_in[3];
    float* out = (float*)d_out;

    int S = in_sizes[3] / Lc;   // sample_k == u == 45

    char* ws = (char*)d_ws;
    float* M     = (float*)ws;                          // 1 MB
    float* Opart = (float*)ws;                          // 5.90 MB (overlaps M)
    float* Mp    = (float*)(ws + 6291456);              // 90 KB
    float* Lp    = (float*)(ws + 6422528);              // 90 KB
    float* bsum  = (float*)(ws + 6815744);              // 256 KB
    int*   top   = (int*)  (ws + 8388608);              // 11.5 KB

    dim3 blk(256);
    if (S == 45)
        k_meas_t<45><<<dim3(Lc / 4, Hc, Bc), blk, 0, stream>>>(Q, K, idx, M);
    else
        k_meas_dyn  <<<dim3(Lc / 4, Hc, Bc), blk, 0, stream>>>(Q, K, idx, M, S);
    k_topk   <<<dim3(Bc * Hc),        blk, 0, stream>>>(M, top, S);
    k_vsum   <<<dim3(VCH, Hc, Bc),    blk, 0, stream>>>(V, bsum);
    k_scan   <<<dim3(VCH, Hc, Bc),    blk, 0, stream>>>(V, bsum, out);
    k_attn2  <<<dim3(NCH, Hc, Bc),    blk, 0, stream>>>(Q, K, V, top, Opart, Mp, Lp, S);
    k_combine<<<dim3(S, Hc, Bc), dim3(64), 0, stream>>>(Opart, Mp, Lp, top, out, S);
}